// Round 4
// baseline (221.969 us; speedup 1.0000x reference)
//
#include <hip/hip_runtime.h>

namespace {

constexpr int BD = 2;
constexpr int DD = 160, HH = 192, WW = 224;
constexpr float INV_WIN = 1.0f / 729.0f;
constexpr float EPSV = 1e-5f;

constexpr int TH = 32, TW = 16;          // output tile (H x W) — TH doubled vs R0
constexpr int DC = 16;                   // output planes per d-chunk (R0 value; R3's 80 regressed)
constexpr int NREAL = DC + 8;            // 24 input plane steps = 12 pairs
constexpr int NPAIR = NREAL / 2;         // 12; superstep loop runs 13, FULLY unrolled
constexpr int NCH = DD / DC;             // 10
constexpr int GX = WW / TW;              // 14
constexpr int GY = HH / TH;              // 6
constexpr int GZ = BD * NCH;             // 20
constexpr int NBLK = GX * GY * GZ;       // 1680 (6.6 blocks/CU: pipelined refill)
constexpr int NXCD = 8;
constexpr int CPX = NBLK / NXCD;         // 210 (1680 % 8 == 0 -> bijective swizzle)
constexpr int IR = TH + 8;               // 40 input rows per block
constexpr double NTOT = (double)BD * DD * HH * WW;

// srow: [buf][plane][field][w*ROWP + row], rows 0..39 (pad ROWP=44).
// Bank residues preserved vs audited R0 layout: ROWP=44 (gcd(44,32)=4, same
// class as 28 -> S2 b32 scatter 2/bank); SR_FS=16*44+4=708 (/4=177 == 1 mod 8
// -> S3 b128 quad-shift 1, uniform); SR_PL=5*708+20=3560 (== 8 mod 32, same
// as 2280). Buf/plane strides wave-uniform.
constexpr int ROWP  = 44;
constexpr int SR_FS = 708;
constexpr int SR_PL = 3560;
// scol: [plane][field][w*OHP + oh], oh 0..31 (pad OHP=36). SC_FS=16*36+4=580
// (/4=145 == 1 mod 8); SC_PL=5*580=2900 (== 20 mod 32, same class as 1620).
// S3 b128 writes: wl3 stride 36 words = 9 quads == 1 mod 8, uniform.
// S4 b32 reads: addr == 4*ow + oh mod 32 -> exactly 2/bank (free).
constexpr int OHP   = 36;
constexpr int SC_FS = 580;
constexpr int SC_PL = 2900;

} // namespace

// R0 pair-superstep structure (two barriers/superstep, full unroll, static
// register D-ring) at TH=32 with 512 threads:
//   - barrier-epochs per output point HALVED (26 barriers amortize 16x32x16
//     outputs instead of 16x16x16)
//   - S2 halo work per output x0.83 (40 rows staged per 32 emitted vs 24/16)
//   - LDS 80.2 KB -> 2 blocks/CU = 16 waves/CU (R0: 12)
// Lessons encoded: R1: NO min-waves launch_bounds (ring spills). R2: do not
// shrink epoch work (single-plane supersteps regressed 1.65x). R3: do not
// shrink the grid to one-shot (672 blocks) or roll the superstep loop
// (runtime guards + imbalance cost 1.6x per-superstep throughput).
// VGPR budget: 2 blocks x 8 waves = 4 waves/SIMD needs VGPR <= 128.
// Measured 96 on the identical-structure R3 body; if this reports >128 the
// residency halves -> that is the failure mode to check first.
__global__ __launch_bounds__(512)
void ncc_fused(const float* __restrict__ x, const float* __restrict__ y,
               float* __restrict__ bsum) {
  const int tid = threadIdx.x;

  // XCD-chunked swizzle (R2/R3-proven: FETCH 348->66 MB): each XCD gets a
  // contiguous chunk of (bx,by,zb) so halo re-reads hit same-XCD L2.
  const int lid = (int)blockIdx.x;
  const int nl  = (lid & (NXCD - 1)) * CPX + (lid >> 3);
  const int zb  = nl / (GX * GY);
  const int rem = nl - zb * (GX * GY);
  const int by  = rem / GX;
  const int bx  = rem - by * GX;

  const int w0 = bx * TW;
  const int h0 = by * TH;
  const int b  = zb / NCH;
  const int d0 = (zb - b * NCH) * DC;

  __shared__ __align__(16) float srowF[2][2 * SR_PL];  // 56960 B (pair dbuf)
  __shared__ __align__(16) float scolF[2 * SC_PL];     // 23200 B
  __shared__ float swsum[8];

  // ---- S2 roles: tids 0..319 = 2 planes x 40 rows x 4 col-segments,
  // 12-wide register window -> 4 sliding 9-tap W-sums x 5 fields.
  const bool s2a = tid < 320;
  const int p2  = tid / 160;           // meaningful only under s2a
  const int t160 = tid - 160 * p2;
  const int r2  = t160 >> 2;           // input row 0..39
  const int seg = tid & 3;             // 160 % 4 == 0 -> tid&3 == t160&3
  const int gh  = h0 - 4 + r2;
  const int gw0 = w0 - 4 + seg * 4;    // 16B aligned
  const bool hok = (unsigned)gh < (unsigned)HH;
  const bool fastw = (gw0 >= 0) && (gw0 + 11 < WW);
  const unsigned plane = (unsigned)HH * WW;

  auto prefetch = [&](int s, float4* vx, float4* vy) {
    const int din = d0 - 4 + s;
    const float4 z = make_float4(0.f, 0.f, 0.f, 0.f);
    vx[0] = vx[1] = vx[2] = z;
    vy[0] = vy[1] = vy[2] = z;
    if (s2a && hok && (s < NREAL) && (din >= 0) && (din < DD)) {
      const unsigned rb = ((unsigned)b * DD + (unsigned)din) * plane + (unsigned)gh * WW;
      if (fastw) {
        const float4* px = (const float4*)(x + rb + gw0);
        const float4* py = (const float4*)(y + rb + gw0);
        vx[0] = px[0]; vx[1] = px[1]; vx[2] = px[2];
        vy[0] = py[0]; vy[1] = py[1]; vy[2] = py[2];
      } else {
        float* fx = (float*)vx;
        float* fy = (float*)vy;
#pragma unroll
        for (int e = 0; e < 12; ++e) {
          const int gw = gw0 + e;
          if ((unsigned)gw < (unsigned)WW) {
            fx[e] = x[rb + gw];
            fy[e] = y[rb + gw];
          }
        }
      }
    }
  };

  // ---- S3 roles: tids 320..479 = 2 planes x 5 fields x 16 w. Each thread
  // H-sums 40 rows -> 32 oh in TWO independent 16-row halves; each half is
  // bit-identical to the R0 16-row block's arithmetic (fresh 9-sum + slide),
  // preserving exactness vs reference.
  const bool s3a = (tid >= 320) && (tid < 480);
  const int t3  = tid - 320;
  const int p3  = t3 / 80;
  const int r3  = t3 - 80 * p3;
  const int f3  = r3 >> 4;
  const int wl3 = r3 & 15;

  const int ow = tid & 15;
  const int oh = tid >> 4;             // 0..31

  // D-ring: 9 slots x 5 fields; slot indices static (loop fully unrolled).
  float rg0[9], rg1[9], rg2[9], rg3[9], rg4[9];
#pragma unroll
  for (int k = 0; k < 9; ++k) { rg0[k]=0.f; rg1[k]=0.f; rg2[k]=0.f; rg3[k]=0.f; rg4[k]=0.f; }
  float a0=0.f, a1=0.f, a2=0.f, a3=0.f, a4=0.f;
  float lsum = 0.0f;

  float4 px4[3], py4[3];
  prefetch(p2, px4, py4);               // pair 0

  // Pipelined supersteps: S2 stages pair ss; S3/S4 consume pair ss-1.
#pragma unroll
  for (int ss = 0; ss <= NPAIR; ++ss) {
    // prefetch pair ss+1 (consumed by S2 next superstep)
    float4 nx4[3], ny4[3];
    if (ss + 1 < NPAIR) prefetch(2 * (ss + 1) + p2, nx4, ny4);

    // ---- S2 (pair ss): W-sums -> srow[ss&1]. Independent of S3 below.
    if (ss < NPAIR && s2a) {
      float xv[12], yv[12];
#pragma unroll
      for (int k = 0; k < 3; ++k) {
        *(float4*)&xv[4 * k] = px4[k];
        *(float4*)&yv[4 * k] = py4[k];
      }
      float s0=0.f, s1=0.f, s2=0.f, s3=0.f, s4=0.f;
#pragma unroll
      for (int k = 0; k < 9; ++k) {
        s0 += xv[k]; s1 += yv[k];
        s2 = fmaf(xv[k], xv[k], s2);
        s3 = fmaf(yv[k], yv[k], s3);
        s4 = fmaf(xv[k], yv[k], s4);
      }
      float* wb = &srowF[ss & 1][p2 * SR_PL + (seg * 4) * ROWP + r2];
      wb[0 * SR_FS] = s0; wb[1 * SR_FS] = s1; wb[2 * SR_FS] = s2;
      wb[3 * SR_FS] = s3; wb[4 * SR_FS] = s4;
#pragma unroll
      for (int t = 1; t < 4; ++t) {
        const float xn = xv[8 + t], xo = xv[t - 1];
        const float yn = yv[8 + t], yo = yv[t - 1];
        s0 += xn - xo;
        s1 += yn - yo;
        s2 += fmaf(xn, xn, -(xo * xo));
        s3 += fmaf(yn, yn, -(yo * yo));
        s4 += fmaf(xn, yn, -(xo * yo));
        float* wt = wb + t * ROWP;
        wt[0 * SR_FS] = s0; wt[1 * SR_FS] = s1; wt[2 * SR_FS] = s2;
        wt[3 * SR_FS] = s3; wt[4 * SR_FS] = s4;
      }
    }

    // ---- S3 (pair ss-1): H-sums from srow[(ss-1)&1] -> scol.
    // No barrier needed vs S2: different srow buffer (written last superstep,
    // separated by barrier E(ss-1)).
    if (ss >= 1 && s3a) {
      const float* rp = &srowF[(ss - 1) & 1][p3 * SR_PL + f3 * SR_FS + wl3 * ROWP];
      float* cp = &scolF[p3 * SC_PL + f3 * SC_FS + wl3 * OHP];
#pragma unroll
      for (int hf = 0; hf < 2; ++hf) {
        const float* rph = rp + 16 * hf;   // rows 16*hf .. 16*hf+23 (64B-aligned)
        float rv[24];
#pragma unroll
        for (int t = 0; t < 6; ++t) *(float4*)&rv[4 * t] = *(const float4*)&rph[4 * t];
        float acc = rv[0];
#pragma unroll
        for (int t = 1; t < 9; ++t) acc += rv[t];
        float ov[16];
        ov[0] = acc;
#pragma unroll
        for (int o = 1; o < 16; ++o) { acc += rv[o + 8] - rv[o - 1]; ov[o] = acc; }
        float* cph = cp + 16 * hf;
#pragma unroll
        for (int t = 0; t < 4; ++t)
          *(float4*)&cph[4 * t] = make_float4(ov[4*t], ov[4*t+1], ov[4*t+2], ov[4*t+3]);
      }
    }
    __syncthreads();   // C: scol visible (also orders S2 writes vs next S3)

    // ---- S4 (pair ss-1): ring update + emit (all 512 threads, oh 0..31)
    if (ss >= 1) {
      const int sA  = 2 * (ss - 1);
      const int sB  = sA + 1;
      const int slA = sA % 9;            // compile-time (full unroll)
      const int slB = sB % 9;
      const float* cA = &scolF[ow * OHP + oh];
      const float* cB = cA + SC_PL;
      const float gA0 = cA[0*SC_FS], gA1 = cA[1*SC_FS], gA2 = cA[2*SC_FS],
                  gA3 = cA[3*SC_FS], gA4 = cA[4*SC_FS];
      const float gB0 = cB[0*SC_FS], gB1 = cB[1*SC_FS], gB2 = cB[2*SC_FS],
                  gB3 = cB[3*SC_FS], gB4 = cB[4*SC_FS];

      a0 += gA0 - rg0[slA]; rg0[slA] = gA0;
      a1 += gA1 - rg1[slA]; rg1[slA] = gA1;
      a2 += gA2 - rg2[slA]; rg2[slA] = gA2;
      a3 += gA3 - rg3[slA]; rg3[slA] = gA3;
      a4 += gA4 - rg4[slA]; rg4[slA] = gA4;
      if (sA >= 8) {
        const float cross = fmaf(-a0 * INV_WIN, a1, a4);
        const float iv = fmaxf(fmaf(-a0 * INV_WIN, a0, a2), EPSV);
        const float jv = fmaxf(fmaf(-a1 * INV_WIN, a1, a3), EPSV);
        lsum += (cross * cross) / (iv * jv);
      }
      a0 += gB0 - rg0[slB]; rg0[slB] = gB0;
      a1 += gB1 - rg1[slB]; rg1[slB] = gB1;
      a2 += gB2 - rg2[slB]; rg2[slB] = gB2;
      a3 += gB3 - rg3[slB]; rg3[slB] = gB3;
      a4 += gB4 - rg4[slB]; rg4[slB] = gB4;
      if (sB >= 8) {
        const float cross = fmaf(-a0 * INV_WIN, a1, a4);
        const float iv = fmaxf(fmaf(-a0 * INV_WIN, a0, a2), EPSV);
        const float jv = fmaxf(fmaf(-a1 * INV_WIN, a1, a3), EPSV);
        lsum += (cross * cross) / (iv * jv);
      }
    }
    __syncthreads();   // E: S4 scol-reads done before S3(ss+1) overwrites;
                       //    S2(ss) srow writes visible to S3(ss+1).
    if (ss + 1 < NPAIR) {
#pragma unroll
      for (int k = 0; k < 3; ++k) { px4[k] = nx4[k]; py4[k] = ny4[k]; }
    }
  }

  // ---- block reduction (8 waves)
#pragma unroll
  for (int off = 32; off > 0; off >>= 1) lsum += __shfl_down(lsum, off);
  if ((tid & 63) == 0) swsum[tid >> 6] = lsum;
  __syncthreads();
  if (tid == 0) {
    float s = 0.f;
#pragma unroll
    for (int k = 0; k < 8; ++k) s += swsum[k];
    bsum[nl] = s;
  }
}

__global__ __launch_bounds__(256)
void ncc_finalize(const float* __restrict__ bsum, float* __restrict__ out) {
  double s = 0.0;
  for (int i = threadIdx.x; i < NBLK; i += 256) s += (double)bsum[i];
#pragma unroll
  for (int off = 32; off > 0; off >>= 1) s += __shfl_down(s, off);
  __shared__ double sh[4];
  if ((threadIdx.x & 63) == 0) sh[threadIdx.x >> 6] = s;
  __syncthreads();
  if (threadIdx.x == 0)
    out[0] = (float)(-(sh[0] + sh[1] + sh[2] + sh[3]) / NTOT);
}

extern "C" void kernel_launch(void* const* d_in, const int* in_sizes, int n_in,
                              void* d_out, int out_size, void* d_ws, size_t ws_size,
                              hipStream_t stream) {
  const float* x = (const float*)d_in[0];
  const float* y = (const float*)d_in[1];
  float* bsum = (float*)d_ws;          // 1680 floats, fully rewritten every call
  float* out  = (float*)d_out;

  ncc_fused<<<dim3(NBLK), dim3(512), 0, stream>>>(x, y, bsum);
  ncc_finalize<<<1, dim3(256), 0, stream>>>(bsum, out);
}

// Round 5
// 209.230 us; speedup vs baseline: 1.0609x; 1.0609x over previous
//
#include <hip/hip_runtime.h>

namespace {

constexpr int BD = 2;
constexpr int DD = 160, HH = 192, WW = 224;
constexpr float INV_WIN = 1.0f / 729.0f;
constexpr float EPSV = 1e-5f;

constexpr int TH = 16, TW = 16;          // output tile (H x W) — R0 shape (best measured)
constexpr int DC = 32;                   // output planes per d-chunk: halo 40/32=1.25x (R0: 1.5x)
constexpr int NREAL = DC + 8;            // 40 plane steps = 20 pairs
constexpr int NPAIR = NREAL / 2;         // 20; superstep loop runs 21, FULLY unrolled
constexpr int NCH = DD / DC;             // 5
constexpr int GX = WW / TW;              // 14
constexpr int GY = HH / TH;              // 12
constexpr int GZ = BD * NCH;             // 10
constexpr int NBLK = GX * GY * GZ;       // 1680 (6.6 blocks/CU: pipelined refill, NOT one-shot)
constexpr int NXCD = 8;
constexpr int CPX = NBLK / NXCD;         // 210 (1680 % 8 == 0 -> bijective swizzle)
constexpr double NTOT = (double)BD * DD * HH * WW;

// srow: [buf][plane][field][w*28 + row], rows 0..23 contiguous (pad 28).
// SR_FS=452 (f-shift /4=113==1 mod 8), SR_PL=2280 (==8 mod 32). Audited (R0):
// S2 b32 scatter 2/bank; S3 b128 reads uniform /quad (incl. straddle waves).
constexpr int SR_FS = 452;
constexpr int SR_PL = 2280;
// scol: [plane][field][w*20 + o]. SC_FS=324, SC_PL=1620. S3 b128 writes
// uniform /quad; S4 b32 reads exactly 2/bank.
constexpr int SC_FS = 324;
constexpr int SC_PL = 1620;

} // namespace

// R0 pair-superstep structure VERBATIM (two barriers/superstep, 192-thread S2
// / 160-thread S3, register D-ring, full unroll) — best measured per-epoch
// efficiency (674 ns/epoch-slot). Session lessons encoded:
//   R1: NO min-waves launch_bounds hint (forces 48 VGPR, ring spills, 3x).
//   R2: do NOT shrink epochs to single-plane (halves per-epoch ILP, 1.65x).
//   R3: do NOT shrink grid to one-shot (672) or roll the superstep loop.
//   R4: do NOT grow block to 512 threads / TH=32 (conflicts 2x/output,
//       8-wave lockstep barriers hide latency worse than 3x4-wave blocks).
// Deltas vs R0 (both counter-attributable):
//   (a) XCD-chunked swizzle — FETCH 348->~70 MB in 3 prior kernels; converts
//       HBM-latency (~900cy) prefetches into L2 hits (~200cy).
//   (b) DC=32 — epochs/output x0.81 at identical epoch shape & residency.
__global__ __launch_bounds__(256)
void ncc_fused(const float* __restrict__ x, const float* __restrict__ y,
               float* __restrict__ bsum) {
  const int tid = threadIdx.x;

  // XCD-chunked swizzle: each XCD gets a contiguous chunk of (bx,by,zb) so
  // halo re-reads of neighboring tiles hit the same-XCD L2.
  const int lid = (int)blockIdx.x;
  const int nl  = (lid & (NXCD - 1)) * CPX + (lid >> 3);
  const int zb  = nl / (GX * GY);
  const int rem = nl - zb * (GX * GY);
  const int by  = rem / GX;
  const int bx  = rem - by * GX;

  const int w0 = bx * TW;
  const int h0 = by * TH;
  const int b  = zb / NCH;
  const int d0 = (zb - b * NCH) * DC;

  __shared__ __align__(16) float srowF[2][2 * SR_PL];  // 36480 B (pair dbuf)
  __shared__ __align__(16) float scolF[2 * SC_PL];     // 12960 B
  __shared__ float swsum[4];

  // ---- S2 roles: tids 0..191 = 2 planes x 24 rows x 4 col-segments,
  // 12-wide register window -> 4 sliding 9-tap W-sums x 5 fields.
  const bool s2a = tid < 192;
  const int p2  = tid / 96;
  const int t96 = tid - 96 * p2;
  const int r2  = t96 >> 2;            // input row 0..23
  const int seg = tid & 3;
  const int gh  = h0 - 4 + r2;
  const int gw0 = w0 - 4 + seg * 4;    // 16B aligned
  const bool hok = (unsigned)gh < (unsigned)HH;
  const bool fastw = (gw0 >= 0) && (gw0 + 11 < WW);
  const unsigned plane = (unsigned)HH * WW;

  auto prefetch = [&](int s, float4* vx, float4* vy) {
    const int din = d0 - 4 + s;
    const float4 z = make_float4(0.f, 0.f, 0.f, 0.f);
    vx[0] = vx[1] = vx[2] = z;
    vy[0] = vy[1] = vy[2] = z;
    if (s2a && hok && (s < NREAL) && (din >= 0) && (din < DD)) {
      const unsigned rb = ((unsigned)b * DD + (unsigned)din) * plane + (unsigned)gh * WW;
      if (fastw) {
        const float4* px = (const float4*)(x + rb + gw0);
        const float4* py = (const float4*)(y + rb + gw0);
        vx[0] = px[0]; vx[1] = px[1]; vx[2] = px[2];
        vy[0] = py[0]; vy[1] = py[1]; vy[2] = py[2];
      } else {
        float* fx = (float*)vx;
        float* fy = (float*)vy;
#pragma unroll
        for (int e = 0; e < 12; ++e) {
          const int gw = gw0 + e;
          if ((unsigned)gw < (unsigned)WW) {
            fx[e] = x[rb + gw];
            fy[e] = y[rb + gw];
          }
        }
      }
    }
  };

  // ---- S3 roles: tids 96..255 = 2 planes x 5 fields x 16 w (wave balance:
  // wave0 S2-only, wave3 S3-only, waves1-2 mixed).
  const int t3  = tid - 96;
  const int p3  = t3 / 80;
  const int r3  = t3 - 80 * p3;
  const int f3  = r3 >> 4;
  const int wl3 = r3 & 15;

  const int ow = tid & 15;
  const int oh = tid >> 4;

  // D-ring: 9 slots x 5 fields; slot indices static after full unroll.
  float rg0[9], rg1[9], rg2[9], rg3[9], rg4[9];
#pragma unroll
  for (int k = 0; k < 9; ++k) { rg0[k]=0.f; rg1[k]=0.f; rg2[k]=0.f; rg3[k]=0.f; rg4[k]=0.f; }
  float a0=0.f, a1=0.f, a2=0.f, a3=0.f, a4=0.f;
  float lsum = 0.0f;

  float4 px4[3], py4[3];
  prefetch(p2, px4, py4);               // pair 0

  // Pipelined supersteps: S2 stages pair ss; S3/S4 consume pair ss-1.
#pragma unroll
  for (int ss = 0; ss <= NPAIR; ++ss) {
    // prefetch pair ss+1 (consumed by S2 next superstep)
    float4 nx4[3], ny4[3];
    if (ss + 1 < NPAIR) prefetch(2 * (ss + 1) + p2, nx4, ny4);

    // ---- S2 (pair ss): W-sums -> srow[ss&1]. Independent of S3 below.
    if (ss < NPAIR && s2a) {
      float xv[12], yv[12];
#pragma unroll
      for (int k = 0; k < 3; ++k) {
        *(float4*)&xv[4 * k] = px4[k];
        *(float4*)&yv[4 * k] = py4[k];
      }
      float s0=0.f, s1=0.f, s2=0.f, s3=0.f, s4=0.f;
#pragma unroll
      for (int k = 0; k < 9; ++k) {
        s0 += xv[k]; s1 += yv[k];
        s2 = fmaf(xv[k], xv[k], s2);
        s3 = fmaf(yv[k], yv[k], s3);
        s4 = fmaf(xv[k], yv[k], s4);
      }
      float* wb = &srowF[ss & 1][p2 * SR_PL + (seg * 4) * 28 + r2];
      wb[0 * SR_FS] = s0; wb[1 * SR_FS] = s1; wb[2 * SR_FS] = s2;
      wb[3 * SR_FS] = s3; wb[4 * SR_FS] = s4;
#pragma unroll
      for (int t = 1; t < 4; ++t) {
        const float xn = xv[8 + t], xo = xv[t - 1];
        const float yn = yv[8 + t], yo = yv[t - 1];
        s0 += xn - xo;
        s1 += yn - yo;
        s2 += fmaf(xn, xn, -(xo * xo));
        s3 += fmaf(yn, yn, -(yo * yo));
        s4 += fmaf(xn, yn, -(xo * yo));
        float* wt = wb + t * 28;
        wt[0 * SR_FS] = s0; wt[1 * SR_FS] = s1; wt[2 * SR_FS] = s2;
        wt[3 * SR_FS] = s3; wt[4 * SR_FS] = s4;
      }
    }

    // ---- S3 (pair ss-1): H-sums from srow[(ss-1)&1] -> scol.
    // No barrier needed vs S2: different srow buffer (written last superstep,
    // separated by barrier E(ss-1)).
    if (ss >= 1 && tid >= 96) {
      const float* rp = &srowF[(ss - 1) & 1][p3 * SR_PL + f3 * SR_FS + wl3 * 28];
      float rv[24];
#pragma unroll
      for (int t = 0; t < 6; ++t) *(float4*)&rv[4 * t] = *(const float4*)&rp[4 * t];
      float acc = rv[0];
#pragma unroll
      for (int t = 1; t < 9; ++t) acc += rv[t];
      float ov[16];
      ov[0] = acc;
#pragma unroll
      for (int o = 1; o < 16; ++o) { acc += rv[o + 8] - rv[o - 1]; ov[o] = acc; }
      float* cp = &scolF[p3 * SC_PL + f3 * SC_FS + wl3 * 20];
#pragma unroll
      for (int t = 0; t < 4; ++t)
        *(float4*)&cp[4 * t] = make_float4(ov[4*t], ov[4*t+1], ov[4*t+2], ov[4*t+3]);
    }
    __syncthreads();   // C: scol visible (also orders S2 writes vs next S3)

    // ---- S4 (pair ss-1): ring update + emit (all 256 threads)
    if (ss >= 1) {
      const int sA  = 2 * (ss - 1);
      const int sB  = sA + 1;
      const int slA = sA % 9;            // compile-time under full unroll
      const int slB = sB % 9;
      const float* cA = &scolF[ow * 20 + oh];
      const float* cB = cA + SC_PL;
      const float gA0 = cA[0*SC_FS], gA1 = cA[1*SC_FS], gA2 = cA[2*SC_FS],
                  gA3 = cA[3*SC_FS], gA4 = cA[4*SC_FS];
      const float gB0 = cB[0*SC_FS], gB1 = cB[1*SC_FS], gB2 = cB[2*SC_FS],
                  gB3 = cB[3*SC_FS], gB4 = cB[4*SC_FS];

      a0 += gA0 - rg0[slA]; rg0[slA] = gA0;
      a1 += gA1 - rg1[slA]; rg1[slA] = gA1;
      a2 += gA2 - rg2[slA]; rg2[slA] = gA2;
      a3 += gA3 - rg3[slA]; rg3[slA] = gA3;
      a4 += gA4 - rg4[slA]; rg4[slA] = gA4;
      if (sA >= 8) {
        const float cross = fmaf(-a0 * INV_WIN, a1, a4);
        const float iv = fmaxf(fmaf(-a0 * INV_WIN, a0, a2), EPSV);
        const float jv = fmaxf(fmaf(-a1 * INV_WIN, a1, a3), EPSV);
        lsum += (cross * cross) / (iv * jv);
      }
      a0 += gB0 - rg0[slB]; rg0[slB] = gB0;
      a1 += gB1 - rg1[slB]; rg1[slB] = gB1;
      a2 += gB2 - rg2[slB]; rg2[slB] = gB2;
      a3 += gB3 - rg3[slB]; rg3[slB] = gB3;
      a4 += gB4 - rg4[slB]; rg4[slB] = gB4;
      if (sB >= 8) {
        const float cross = fmaf(-a0 * INV_WIN, a1, a4);
        const float iv = fmaxf(fmaf(-a0 * INV_WIN, a0, a2), EPSV);
        const float jv = fmaxf(fmaf(-a1 * INV_WIN, a1, a3), EPSV);
        lsum += (cross * cross) / (iv * jv);
      }
    }
    __syncthreads();   // E: S4 scol-reads done before S3(ss+1) overwrites;
                       //    S2(ss) srow writes visible to S3(ss+1).
    if (ss + 1 < NPAIR) {
#pragma unroll
      for (int k = 0; k < 3; ++k) { px4[k] = nx4[k]; py4[k] = ny4[k]; }
    }
  }

  // ---- block reduction
#pragma unroll
  for (int off = 32; off > 0; off >>= 1) lsum += __shfl_down(lsum, off);
  if ((tid & 63) == 0) swsum[tid >> 6] = lsum;
  __syncthreads();
  if (tid == 0) bsum[nl] = swsum[0] + swsum[1] + swsum[2] + swsum[3];
}

__global__ __launch_bounds__(256)
void ncc_finalize(const float* __restrict__ bsum, float* __restrict__ out) {
  double s = 0.0;
  for (int i = threadIdx.x; i < NBLK; i += 256) s += (double)bsum[i];
#pragma unroll
  for (int off = 32; off > 0; off >>= 1) s += __shfl_down(s, off);
  __shared__ double sh[4];
  if ((threadIdx.x & 63) == 0) sh[threadIdx.x >> 6] = s;
  __syncthreads();
  if (threadIdx.x == 0)
    out[0] = (float)(-(sh[0] + sh[1] + sh[2] + sh[3]) / NTOT);
}

extern "C" void kernel_launch(void* const* d_in, const int* in_sizes, int n_in,
                              void* d_out, int out_size, void* d_ws, size_t ws_size,
                              hipStream_t stream) {
  const float* x = (const float*)d_in[0];
  const float* y = (const float*)d_in[1];
  float* bsum = (float*)d_ws;          // 1680 floats, fully rewritten every call
  float* out  = (float*)d_out;

  ncc_fused<<<dim3(NBLK), dim3(256), 0, stream>>>(x, y, bsum);
  ncc_finalize<<<1, dim3(256), 0, stream>>>(bsum, out);
}